// Round 5
// baseline (28.777 us; speedup 1.0000x reference)
//
#include <hip/hip_runtime.h>

#define CROP 7
#define CH 256
#define NBOX 512
#define IMH 200
#define IMW 304
#define PLANE (IMH * IMW)   // 60800
#define NXCD 8
#define CPT 8               // channels per thread

__device__ __forceinline__ float2 ld2(const float* __restrict__ p) {
    float2 v;
    __builtin_memcpy(&v, p, sizeof(float2));  // 4B-aligned dwordx2
    return v;
}

__global__ __launch_bounds__(256) void roialign_kernel(
    const float* __restrict__ fm, const float* __restrict__ boxes,
    const int* __restrict__ box_ind, float* __restrict__ out)
{
    // total threads = NBOX * 49 * (CH/CPT) = 512*49*32 -> 3136 blocks
    const int nblocks = (NBOX * 49 * (CH / CPT)) / 256;   // 3136, %8==0
    const int chunk = nblocks / NXCD;                      // 392
    int b = blockIdx.x;
    int newb = (b % NXCD) * chunk + b / NXCD;  // XCD k owns contiguous cblk range

    // e enumerated: cblk OUTER, m middle, s=(iy,ix) inner
    int e = newb * 256 + threadIdx.x;
    int s = e % 49;
    int t = e / 49;
    int m = t % NBOX;
    int cblk = t / NBOX;          // 0..31
    int c0 = cblk * CPT;
    int ix = s % CROP;
    int iy = s / CROP;

    float x1 = boxes[4 * m + 0];
    float y1 = boxes[4 * m + 1];
    float x2 = boxes[4 * m + 2];
    float y2 = boxes[4 * m + 3];

    const float Wm1 = (float)(IMW - 1);
    const float Hm1 = (float)(IMH - 1);

    // replicate reference(): normalize
    float spacing_w = (x2 - x1) / (float)CROP;
    float spacing_h = (y2 - y1) / (float)CROP;
    float nx0 = (x1 + spacing_w * 0.5f - 0.5f) / Wm1;
    float ny0 = (y1 + spacing_h * 0.5f - 0.5f) / Hm1;
    float nw = spacing_w * (float)(CROP - 1) / Wm1;
    float nh = spacing_h * (float)(CROP - 1) / Hm1;

    // replicate _crop_and_resize(): denormalize
    float h_scale = nh * Hm1 / (float)(CROP - 1);
    float w_scale = nw * Wm1 / (float)(CROP - 1);
    float in_y = ny0 * Hm1 + (float)iy * h_scale;
    float in_x = nx0 * Wm1 + (float)ix * w_scale;

    bool valid = (in_y >= 0.0f) && (in_y <= Hm1) && (in_x >= 0.0f) && (in_x <= Wm1);

    float top   = floorf(in_y);
    float left  = floorf(in_x);
    float bot   = ceilf(in_y);
    float ly = in_y - top;
    float lx = in_x - left;

    int ti = (int)fminf(fmaxf(top,  0.0f), Hm1);
    int bi = (int)fminf(fmaxf(bot,  0.0f), Hm1);
    int li = (int)fminf(fmaxf(left, 0.0f), Wm1);

    int cb = li < (IMW - 2) ? li : (IMW - 2);   // merged-load base column
    bool sel = (li > cb);                        // li == W-1 -> take .y

    int off_t = ti * IMW + cb;
    int off_b = bi * IMW + cb;

    int bimg = box_ind[m];
    const float* __restrict__ p = fm + ((size_t)bimg * CH + c0) * (size_t)PLANE;

    // 16 independent 8B gathers (8 channels x {top,bottom} row pairs)
    float2 tv[CPT], bv[CPT];
#pragma unroll
    for (int k = 0; k < CPT; ++k) {
        tv[k] = ld2(p + off_t + k * PLANE);
        bv[k] = ld2(p + off_b + k * PLANE);
    }

    int obase = (m * CH + c0) * 49 + s;
#pragma unroll
    for (int k = 0; k < CPT; ++k) {
        // tl = sel ? .y : .x ; tr = .y (when .y isn't the true tr, lx==0 or invalid)
        float tl = sel ? tv[k].y : tv[k].x;
        float bl = sel ? bv[k].y : bv[k].x;
        float tvv = tl + (tv[k].y - tl) * lx;
        float bvv = bl + (bv[k].y - bl) * lx;
        float v = tvv + (bvv - tvv) * ly;
        v = valid ? v : 0.0f;
        __builtin_nontemporal_store(v, &out[obase + k * 49]);
    }
}

extern "C" void kernel_launch(void* const* d_in, const int* in_sizes, int n_in,
                              void* d_out, int out_size, void* d_ws, size_t ws_size,
                              hipStream_t stream) {
    const float* fm      = (const float*)d_in[0];
    const float* boxes   = (const float*)d_in[1];
    const int*   box_ind = (const int*)d_in[2];
    float*       out     = (float*)d_out;

    int grid = (NBOX * 49 * (CH / CPT)) / 256;  // 3136
    roialign_kernel<<<grid, 256, 0, stream>>>(fm, boxes, box_ind, out);
}

// Round 6
// 28.135 us; speedup vs baseline: 1.0228x; 1.0228x over previous
//
#include <hip/hip_runtime.h>

#define CROP 7
#define CH 256
#define NBOX 512
#define IMH 200
#define IMW 304
#define PLANE (IMH * IMW)   // 60800
#define NXCD 8
#define CPT 4               // channels per thread (CPT=8 measured flat/worse)

__device__ __forceinline__ float2 ld2(const float* __restrict__ p) {
    float2 v;
    __builtin_memcpy(&v, p, sizeof(float2));  // 4B-aligned dwordx2
    return v;
}

__global__ __launch_bounds__(256) void roialign_kernel(
    const float* __restrict__ fm, const float* __restrict__ boxes,
    const int* __restrict__ box_ind, float* __restrict__ out)
{
    // total threads = NBOX * 49 * (CH/CPT) = 512*49*64 -> 6272 blocks
    const int nblocks = (NBOX * 49 * (CH / CPT)) / 256;   // 6272, %8==0
    const int chunk = nblocks / NXCD;                      // 784
    int b = blockIdx.x;
    int newb = (b % NXCD) * chunk + b / NXCD;  // XCD k owns contiguous cblk range

    // e enumerated: cblk OUTER, m middle, s=(iy,ix) inner
    int e = newb * 256 + threadIdx.x;
    int s = e % 49;
    int t = e / 49;
    int m = t % NBOX;
    int cblk = t / NBOX;          // 0..63
    int c0 = cblk * CPT;
    int ix = s % CROP;
    int iy = s / CROP;

    float x1 = boxes[4 * m + 0];
    float y1 = boxes[4 * m + 1];
    float x2 = boxes[4 * m + 2];
    float y2 = boxes[4 * m + 3];

    const float Wm1 = (float)(IMW - 1);
    const float Hm1 = (float)(IMH - 1);

    // replicate reference(): normalize
    float spacing_w = (x2 - x1) / (float)CROP;
    float spacing_h = (y2 - y1) / (float)CROP;
    float nx0 = (x1 + spacing_w * 0.5f - 0.5f) / Wm1;
    float ny0 = (y1 + spacing_h * 0.5f - 0.5f) / Hm1;
    float nw = spacing_w * (float)(CROP - 1) / Wm1;
    float nh = spacing_h * (float)(CROP - 1) / Hm1;

    // replicate _crop_and_resize(): denormalize
    float h_scale = nh * Hm1 / (float)(CROP - 1);
    float w_scale = nw * Wm1 / (float)(CROP - 1);
    float in_y = ny0 * Hm1 + (float)iy * h_scale;
    float in_x = nx0 * Wm1 + (float)ix * w_scale;

    bool valid = (in_y >= 0.0f) && (in_y <= Hm1) && (in_x >= 0.0f) && (in_x <= Wm1);

    float top   = floorf(in_y);
    float left  = floorf(in_x);
    float bot   = ceilf(in_y);
    float ly = in_y - top;
    float lx = in_x - left;

    int ti = (int)fminf(fmaxf(top,  0.0f), Hm1);
    int bi = (int)fminf(fmaxf(bot,  0.0f), Hm1);
    int li = (int)fminf(fmaxf(left, 0.0f), Wm1);

    int cb = li < (IMW - 2) ? li : (IMW - 2);   // merged-load base column
    bool sel = (li > cb);                        // li == W-1 -> take .y

    int off_t = ti * IMW + cb;
    int off_b = bi * IMW + cb;

    int bimg = box_ind[m];
    const float* __restrict__ p = fm + ((size_t)bimg * CH + c0) * (size_t)PLANE;

    // 8 independent 8B gathers (4 channels x {top,bottom} row pairs)
    float2 t0 = ld2(p + off_t);             float2 b0 = ld2(p + off_b);
    float2 t1 = ld2(p + off_t + PLANE);     float2 b1 = ld2(p + off_b + PLANE);
    float2 t2 = ld2(p + off_t + 2*PLANE);   float2 b2 = ld2(p + off_b + 2*PLANE);
    float2 t3 = ld2(p + off_t + 3*PLANE);   float2 b3 = ld2(p + off_b + 3*PLANE);

    // tl = sel ? .y : .x ; tr = .y (whenever .y is not the true tr, lx==0 or invalid)
    float tl0 = sel ? t0.y : t0.x, bl0 = sel ? b0.y : b0.x;
    float tl1 = sel ? t1.y : t1.x, bl1 = sel ? b1.y : b1.x;
    float tl2 = sel ? t2.y : t2.x, bl2 = sel ? b2.y : b2.x;
    float tl3 = sel ? t3.y : t3.x, bl3 = sel ? b3.y : b3.x;

    float tv0 = tl0 + (t0.y - tl0) * lx, bv0 = bl0 + (b0.y - bl0) * lx;
    float tv1 = tl1 + (t1.y - tl1) * lx, bv1 = bl1 + (b1.y - bl1) * lx;
    float tv2 = tl2 + (t2.y - tl2) * lx, bv2 = bl2 + (b2.y - bl2) * lx;
    float tv3 = tl3 + (t3.y - tl3) * lx, bv3 = bl3 + (b3.y - bl3) * lx;

    float v0 = tv0 + (bv0 - tv0) * ly;
    float v1 = tv1 + (bv1 - tv1) * ly;
    float v2 = tv2 + (bv2 - tv2) * ly;
    float v3 = tv3 + (bv3 - tv3) * ly;
    if (!valid) { v0 = 0.0f; v1 = 0.0f; v2 = 0.0f; v3 = 0.0f; }

    // out layout: [m][c][iy][ix]; channel stride = 49 floats
    int obase = (m * CH + c0) * 49 + s;
    __builtin_nontemporal_store(v0, &out[obase]);
    __builtin_nontemporal_store(v1, &out[obase + 49]);
    __builtin_nontemporal_store(v2, &out[obase + 2*49]);
    __builtin_nontemporal_store(v3, &out[obase + 3*49]);
}

extern "C" void kernel_launch(void* const* d_in, const int* in_sizes, int n_in,
                              void* d_out, int out_size, void* d_ws, size_t ws_size,
                              hipStream_t stream) {
    const float* fm      = (const float*)d_in[0];
    const float* boxes   = (const float*)d_in[1];
    const int*   box_ind = (const int*)d_in[2];
    float*       out     = (float*)d_out;

    int grid = (NBOX * 49 * (CH / CPT)) / 256;  // 6272
    roialign_kernel<<<grid, 256, 0, stream>>>(fm, boxes, box_ind, out);
}